// Round 11
// baseline (126.379 us; speedup 1.0000x reference)
//
#include <hip/hip_runtime.h>
#include <hip/hip_bf16.h>
#include <math.h>

// Problem constants
constexpr int cHW   = 4096;   // H*W
constexpr int cC    = 128;
constexpr int cNH   = 4;
constexpr int cDH   = 32;
constexpr float cEPS = 1e-5f;
// dh^-0.5 * log2(e): scores in log2 domain, softmax via exp2, fixed max=0
constexpr float cQS = 0.2550347805f;
// SPLIT=4 (R5/R6: SPLIT=8 costs +4.2us opart traffic, no occupancy payoff).
// R10 structure (124.9us): fused out_fused (in-register combine, non-atomic
// stats partials). R11: flash K/V register-rotation prefetch (loads for
// tile i+1 issued before compute of tile i) to cut the per-tile L2-latency
// stall that left VALUBusy at 27%.
constexpr int SPLIT = 4;

typedef short bh8  __attribute__((ext_vector_type(8)));   // 8 bf16 (4 VGPRs)
typedef float f4   __attribute__((ext_vector_type(4)));   // MFMA C/D 16x16
typedef float f16a __attribute__((ext_vector_type(16)));  // MFMA C/D 32x32

static __device__ __forceinline__ unsigned short f2bf(float f) {
  union { __hip_bfloat16 h; unsigned short u; } cv;
  cv.h = __float2bfloat16(f);
  return cv.u;
}
static __device__ __forceinline__ unsigned pack2bf(float a, float b) {
  return (unsigned)f2bf(a) | ((unsigned)f2bf(b) << 16);
}
// truncating pack: 2 VALU. Error cancels in softmax since l is computed from
// the same truncated P via MFMA-with-ones.
static __device__ __forceinline__ unsigned pack_trunc(float a, float b) {
  unsigned ua = __builtin_bit_cast(unsigned, a);
  unsigned ub = __builtin_bit_cast(unsigned, b);
  return (ua >> 16) | (ub & 0xffff0000u);
}
static __device__ __forceinline__ float bflo(unsigned pk) {
  return __builtin_bit_cast(float, pk << 16);
}
static __device__ __forceinline__ float bfhi(unsigned pk) {
  return __builtin_bit_cast(float, pk & 0xffff0000u);
}
// v_permlane32_swap_b32: dst lanes 32-63 <-> src lanes 0-31
static __device__ __forceinline__ void plswap(unsigned& a, unsigned& b) {
#if __has_builtin(__builtin_amdgcn_permlane32_swap)
  typedef int v2i __attribute__((ext_vector_type(2)));
  v2i r = __builtin_amdgcn_permlane32_swap((int)a, (int)b, false, false);
  a = (unsigned)r[0]; b = (unsigned)r[1];
#else
  asm("v_permlane32_swap_b32 %0, %1" : "+v"(a), "+v"(b));
#endif
}
static __device__ __forceinline__ bh8 mk8(unsigned a, unsigned b, unsigned c, unsigned d) {
  union { unsigned u[4]; bh8 v; } t;
  t.u[0] = a; t.u[1] = b; t.u[2] = c; t.u[3] = d;
  return t.v;
}

// ---------------- block reduce (sum of two values over 256 threads) -------
__device__ __forceinline__ void block_reduce2(float& a, float& b, float* sbuf) {
  #pragma unroll
  for (int off = 32; off > 0; off >>= 1) {
    a += __shfl_down(a, off, 64);
    b += __shfl_down(b, off, 64);
  }
  int wave = threadIdx.x >> 6;
  int lane = threadIdx.x & 63;
  if (lane == 0) { sbuf[wave] = a; sbuf[4 + wave] = b; }
  __syncthreads();
  if (threadIdx.x == 0) {
    sbuf[8] = sbuf[0] + sbuf[1] + sbuf[2] + sbuf[3];
    sbuf[9] = sbuf[4] + sbuf[5] + sbuf[6] + sbuf[7];
  }
  __syncthreads();
  a = sbuf[8];
  b = sbuf[9];
}

// ---------------- prep: GN1 stats partials + weight transpose/pack --------
__global__ __launch_bounds__(256)
void prep(const float* __restrict__ x, float* __restrict__ part,
          const float* __restrict__ wq, const float* __restrict__ wo,
          unsigned short* __restrict__ wqT, unsigned short* __restrict__ woT) {
  __shared__ float lds[32 * 133];
  int L = threadIdx.x;
  if (blockIdx.x < 256) {
    int ng = blockIdx.x >> 3, sl = blockIdx.x & 7;
    const float4* s4 = (const float4*)x;
    float s = 0.f, s2 = 0.f;
    #pragma unroll
    for (int i = 0; i < 4; i++) {
      int idx = i * 256 + L;
      int c = idx >> 7, tt = idx & 127;
      float4 v = s4[(size_t)(ng * 8 + c) * 1024 + sl * 128 + tt];
      s  += v.x + v.y + v.z + v.w;
      s2 += v.x*v.x + v.y*v.y + v.z*v.z + v.w*v.w;
    }
    block_reduce2(s, s2, lds);
    if (L == 0) { part[blockIdx.x * 2] = s; part[blockIdx.x * 2 + 1] = s2; }
  } else {
    int bx = blockIdx.x - 256;
    const float* src; unsigned short* dst; int W, d0;
    if (bx < 12) { src = wq; dst = wqT; W = 384; d0 = bx * 32; }
    else         { src = wo; dst = woT; W = 128; d0 = (bx - 12) * 32; }
    #pragma unroll
    for (int i = 0; i < 16; i++) {
      int c = i * 8 + (L >> 5), d = L & 31;
      lds[d * 133 + c] = src[(size_t)c * W + d0 + d];
    }
    __syncthreads();
    int d = L >> 3, ch = L & 7, c0 = ch * 16;
    unsigned pk[8];
    #pragma unroll
    for (int j = 0; j < 8; j++)
      pk[j] = pack2bf(lds[d * 133 + c0 + 2 * j], lds[d * 133 + c0 + 2 * j + 1]);
    uint4* d4 = (uint4*)(dst + (size_t)(d0 + d) * 128 + c0);
    d4[0] = make_uint4(pk[0], pk[1], pk[2], pk[3]);
    d4[1] = make_uint4(pk[4], pk[5], pk[6], pk[7]);
  }
}

// ---------------- GN1 apply + bf16 chunk pack -----------------------------
// xnB layout: [n][16 cc][4096 t][8 c] bf16
__global__ __launch_bounds__(256)
void gn1_pack(const float* __restrict__ x, const float* __restrict__ part,
              const float* __restrict__ sc, const float* __restrict__ of,
              unsigned short* __restrict__ xnB) {
  int cc = blockIdx.x, ts = blockIdx.y, n = blockIdx.z;
  int ng = n * 16 + cc;
  float s = 0.f, s2 = 0.f;
  #pragma unroll
  for (int p = 0; p < 8; p++) { s += part[(ng*8+p)*2]; s2 += part[(ng*8+p)*2+1]; }
  float mu = s * (1.0f / 32768.0f);
  float rinv = rsqrtf(s2 * (1.0f / 32768.0f) - mu * mu + cEPS);
  int t = ts * 256 + threadIdx.x;
  float v[8];
  #pragma unroll
  for (int j = 0; j < 8; j++) {
    int c = cc * 8 + j;
    float a = rinv * sc[c];
    float bo = of[c] - mu * a;
    v[j] = x[((size_t)n * cC + c) * cHW + t] * a + bo;
  }
  unsigned pk[4];
  #pragma unroll
  for (int j = 0; j < 4; j++) pk[j] = pack2bf(v[2*j], v[2*j+1]);
  ((uint4*)xnB)[(size_t)(n * 16 + cc) * cHW + t] = make_uint4(pk[0], pk[1], pk[2], pk[3]);
}

// ---------------- QKV projection (MFMA) -> FRAGMENT-MAJOR Q/K/V -----------
// grid (64 tt, 12 dg, 2 n), block 256 (4 waves x 16 t-rows).
// Output layouts are exactly the order flash_mfma's waves consume:
//   qF/kF: [nh][tile=key/32][frag=dh/16][L=hi*32+col] bh8, elem j -> dh=frag*16+hi*8+j, key=tile*32+col
//   vF   : [nh][tile]       [frag=kk/16][L=hi*32+col] bh8, elem j -> d=col, key=tile*32+frag*16+hi*8+j
// so every flash load is lane-consecutive (fully coalesced).
__global__ __launch_bounds__(256)
void qkv_mfma(const unsigned short* __restrict__ xnB, const unsigned short* __restrict__ wqT,
              const float* __restrict__ bq, unsigned* __restrict__ qF,
              unsigned* __restrict__ kF, unsigned* __restrict__ vF) {
  __shared__ float vbuf[64 * 36];
  const int L = threadIdx.x & 63, w = threadIdx.x >> 6;
  const int c16 = L & 15, q = L >> 4;
  const int t0 = blockIdx.x * 64, dg = blockIdx.y, n = blockIdx.z;
  const int nh = n * 4 + (dg & 3), d0 = dg * 32;
  const f4 zf = {0.f, 0.f, 0.f, 0.f};
  f4 acc0 = zf, acc1 = zf;
  const int trow = t0 + w * 16 + c16;
  #pragma unroll
  for (int ks = 0; ks < 4; ks++) {
    bh8 a  = *(const bh8*)(xnB + ((size_t)(n * 16 + ks * 4 + q) * cHW + trow) * 8);
    bh8 b0 = *(const bh8*)(wqT + (size_t)(d0 + c16) * 128 + ks * 32 + q * 8);
    bh8 b1 = *(const bh8*)(wqT + (size_t)(d0 + 16 + c16) * 128 + ks * 32 + q * 8);
    acc0 = __builtin_amdgcn_mfma_f32_16x16x32_bf16(a, b0, acc0, 0, 0, 0);
    acc1 = __builtin_amdgcn_mfma_f32_16x16x32_bf16(a, b1, acc1, 0, 0, 0);
  }
  const float blo = bq[d0 + c16], bhi = bq[d0 + 16 + c16];
  const float scl = (dg < 4) ? cQS : 1.0f;
  // stage [row=t-t0][dh 0..31] (pad 36)
  #pragma unroll
  for (int r = 0; r < 4; r++) {
    vbuf[(w * 16 + q * 4 + r) * 36 + c16]      = (acc0[r] + blo) * scl;
    vbuf[(w * 16 + q * 4 + r) * 36 + 16 + c16] = (acc1[r] + bhi) * scl;
  }
  __syncthreads();
  // fragment-major pack: 256 threads = 2 tiles x 2 frags x 64 lanes
  const int tl = threadIdx.x >> 7, fr = (threadIdx.x >> 6) & 1, LL = threadIdx.x & 63;
  const int col = LL & 31, h2 = LL >> 5;
  unsigned pk[4];
  if (dg < 8) {
    const float* src = &vbuf[(tl * 32 + col) * 36 + fr * 16 + h2 * 8];
    #pragma unroll
    for (int jj = 0; jj < 4; jj++) pk[jj] = pack2bf(src[2 * jj], src[2 * jj + 1]);
  } else {
    const float* src = &vbuf[(tl * 32 + fr * 16 + h2 * 8) * 36 + col];
    #pragma unroll
    for (int jj = 0; jj < 4; jj++) pk[jj] = pack2bf(src[2 * jj * 36], src[(2 * jj + 1) * 36]);
  }
  unsigned* dst = (dg < 4) ? qF : ((dg < 8) ? kF : vF);
  size_t frag = ((size_t)(nh * 128 + (t0 >> 5) + tl) * 2 + fr) * 64 + LL;
  ((uint4*)dst)[frag] = make_uint4(pk[0], pk[1], pk[2], pk[3]);
}

// ---------------- MFMA flash attention, swapped-QK 32x32, zero LDS --------
// R11: K/V REGISTER-ROTATION PREFETCH. Loads for tile i+1 are issued before
// the compute of tile i, so the ~300cy L2 latency overlaps the ~200cy
// exp2/pack/MFMA chain instead of serializing with it (R2 PMC: VALUBusy 27%
// = latency-bound). +16 VGPR (52 -> ~70), still within the <=128 granule so
// the grid's 16 waves/CU all fit — prefetch registers are occupancy-free.
// grid (64 qb, 8 nh, SPLIT), block 128 (2 waves, 1 q-tile each).
__global__ __launch_bounds__(128, 4)
void flash_mfma(const unsigned short* __restrict__ qF,
                const unsigned short* __restrict__ kF,
                const unsigned short* __restrict__ vF,
                unsigned* __restrict__ opart, float* __restrict__ lpart) {
  const int w = threadIdx.x >> 6, L = threadIdx.x & 63;
  const int col = L & 31, hi = L >> 5;
  const int qt = blockIdx.x * 2 + w, nh = blockIdx.y, ph = blockIdx.z;
  const short oneb = 0x3F80;        // bf16 1.0
  const bh8 ones = {oneb, oneb, oneb, oneb, oneb, oneb, oneb, oneb};
  const f16a zf16 = {0.f,0.f,0.f,0.f, 0.f,0.f,0.f,0.f, 0.f,0.f,0.f,0.f, 0.f,0.f,0.f,0.f};

  // Q fragments (coalesced: lane L reads 16B at L*16)
  const unsigned short* qb = qF + ((size_t)(nh * 128 + qt) * 2) * 512;
  bh8 qf0 = *(const bh8*)(qb + L * 8);
  bh8 qf1 = *(const bh8*)(qb + 512 + L * 8);

  const unsigned short* kb = kF + (size_t)nh * 128 * 1024;
  const unsigned short* vb = vF + (size_t)nh * 128 * 1024;

  f16a o = zf16, lacc = zf16;

  const int tb0 = ph * (cHW / SPLIT / 32);   // 32 key-tiles per split
  const int tend = tb0 + (cHW / SPLIT / 32);

  // prologue: load tile tb0 fragments
  bh8 ka0 = *(const bh8*)(kb + (size_t)tb0 * 1024 + L * 8);
  bh8 ka1 = *(const bh8*)(kb + (size_t)tb0 * 1024 + 512 + L * 8);
  bh8 vfa = *(const bh8*)(vb + (size_t)tb0 * 1024 + L * 8);
  bh8 vfb = *(const bh8*)(vb + (size_t)tb0 * 1024 + 512 + L * 8);

  for (int tl = tb0; tl < tend; ++tl) {
    // issue NEXT tile's loads before this tile's compute (clamped index:
    // last iteration re-loads tb0 harmlessly; values unused)
    const int ntl = (tl + 1 < tend) ? tl + 1 : tb0;
    const unsigned short* nkp = kb + (size_t)ntl * 1024;
    const unsigned short* nvp = vb + (size_t)ntl * 1024;
    bh8 nka0 = *(const bh8*)(nkp + L * 8);
    bh8 nka1 = *(const bh8*)(nkp + 512 + L * 8);
    bh8 nvfa = *(const bh8*)(nvp + L * 8);
    bh8 nvfb = *(const bh8*)(nvp + 512 + L * 8);

    f16a s = __builtin_amdgcn_mfma_f32_32x32x16_bf16(ka0, qf0, zf16, 0, 0, 0);
    s = __builtin_amdgcn_mfma_f32_32x32x16_bf16(ka1, qf1, s, 0, 0, 0);
    // softmax numerator (fixed max 0), truncating bf16 pack
    #pragma unroll
    for (int r = 0; r < 16; r++) s[r] = __builtin_amdgcn_exp2f(s[r]);
    // pk holds key pairs; lane(hi) owns keys (reg&3)+8*(reg>>2)+4*hi
    unsigned pk0 = pack_trunc(s[0],  s[1]);
    unsigned pk1 = pack_trunc(s[2],  s[3]);
    unsigned pk2 = pack_trunc(s[4],  s[5]);
    unsigned pk3 = pack_trunc(s[6],  s[7]);
    unsigned pk4 = pack_trunc(s[8],  s[9]);
    unsigned pk5 = pack_trunc(s[10], s[11]);
    unsigned pk6 = pack_trunc(s[12], s[13]);
    unsigned pk7 = pack_trunc(s[14], s[15]);
    // redistribute into A-frag word order: one swap yields words 0 and 2
    plswap(pk0, pk2); plswap(pk1, pk3);   // keys tile+0..15
    plswap(pk4, pk6); plswap(pk5, pk7);   // keys tile+16..31
    bh8 pf0 = mk8(pk0, pk1, pk2, pk3);
    bh8 pf1 = mk8(pk4, pk5, pk6, pk7);
    o    = __builtin_amdgcn_mfma_f32_32x32x16_bf16(pf0, vfa,  o,    0, 0, 0);
    lacc = __builtin_amdgcn_mfma_f32_32x32x16_bf16(pf0, ones, lacc, 0, 0, 0);
    o    = __builtin_amdgcn_mfma_f32_32x32x16_bf16(pf1, vfb,  o,    0, 0, 0);
    lacc = __builtin_amdgcn_mfma_f32_32x32x16_bf16(pf1, ones, lacc, 0, 0, 0);

    // rotate prefetched fragments into place
    ka0 = nka0; ka1 = nka1; vfa = nvfa; vfb = nvfb;
  }

  // epilogue: lane(hi,col) holds O[row][d=col] for rows (reg&3)+8*(reg>>2)+4*hi.
  // opart: u32 packs ROW pairs (even,odd) at [(globalrow/2)*32 + d].
  const size_t base = (size_t)ph * 32768 + (size_t)nh * cHW + (size_t)qt * 32;
  #pragma unroll
  for (int k = 0; k < 8; k++) {
    const int rowlo = ((2 * k) & 3) + 8 * (k >> 1) + 4 * hi;
    opart[((base + rowlo) >> 1) * 32 + col] = pack_trunc(o[2 * k], o[2 * k + 1]);
  }
  if (col == 0) {
    #pragma unroll
    for (int r = 0; r < 16; r++)
      lpart[base + (r & 3) + 8 * (r >> 2) + 4 * hi] = lacc[r];
  }
}

// ---------------- fused: in-register combine + out projection + stats -----
// grid (64 tt, 4 dg, 2 n), block 256 (4 waves) — R10-proven form.
// In-register split-K combine feeds the out-projection A-fragments directly;
// GN2 stats as per-(block,wave,hh) NON-atomic partials (R8 lesson).
// part2 layout: [n][g 16][slot 128 = tt*2+(w&1)][2: sum,sumsq]
__global__ __launch_bounds__(256)
void out_fused(const unsigned* __restrict__ opart, const float* __restrict__ lpart,
               const unsigned short* __restrict__ woT, const float* __restrict__ bo,
               float* __restrict__ proj, float* __restrict__ part2) {
  __shared__ float obuf[64 * 36];
  const int L = threadIdx.x & 63, w = threadIdx.x >> 6;
  const int c16 = L & 15, q = L >> 4;
  const int t0 = blockIdx.x * 64, d0 = blockIdx.y * 32, n = blockIdx.z;
  const f4 zf = {0.f, 0.f, 0.f, 0.f};
  const int trow = t0 + w * 16 + c16;

  // ---- in-register split-K combine: A-fragment per head ----
  bh8 afrag[4];
  #pragma unroll
  for (int h = 0; h < 4; h++) {
    const size_t grow = (size_t)(n * 4 + h) * cHW + trow;
    float l = 0.f;
    #pragma unroll
    for (int p = 0; p < SPLIT; p++) l += lpart[(size_t)p * 32768 + grow];
    const size_t rp = grow >> 1;
    const int par = c16 & 1;            // row parity: lo=even row, hi=odd
    float e[8];
    #pragma unroll
    for (int j = 0; j < 8; j++) e[j] = 0.f;
    #pragma unroll
    for (int p = 0; p < SPLIT; p++) {
      const uint4* op = (const uint4*)(opart + ((size_t)p * 16384 + rp) * 32 + q * 8);
      uint4 v0 = op[0], v1 = op[1];
      unsigned uu[8] = {v0.x, v0.y, v0.z, v0.w, v1.x, v1.y, v1.z, v1.w};
      #pragma unroll
      for (int j = 0; j < 8; j++)
        e[j] += par ? bfhi(uu[j]) : bflo(uu[j]);
    }
    const float inv = 1.0f / l;
    unsigned pk[4];
    #pragma unroll
    for (int jj = 0; jj < 4; jj++)
      pk[jj] = pack2bf(e[2 * jj] * inv, e[2 * jj + 1] * inv);
    afrag[h] = mk8(pk[0], pk[1], pk[2], pk[3]);
  }

  // ---- out-projection MFMA (A straight from registers) ----
  f4 acc0 = zf, acc1 = zf;
  #pragma unroll
  for (int h = 0; h < 4; h++) {
    bh8 b0 = *(const bh8*)(woT + (size_t)(d0 + c16) * 128 + h * 32 + q * 8);
    bh8 b1 = *(const bh8*)(woT + (size_t)(d0 + 16 + c16) * 128 + h * 32 + q * 8);
    acc0 = __builtin_amdgcn_mfma_f32_16x16x32_bf16(afrag[h], b0, acc0, 0, 0, 0);
    acc1 = __builtin_amdgcn_mfma_f32_16x16x32_bf16(afrag[h], b1, acc1, 0, 0, 0);
  }
  float blo = bo[d0 + c16], bhi = bo[d0 + 16 + c16];
  #pragma unroll
  for (int r = 0; r < 4; r++) {
    obuf[(w * 16 + q * 4 + r) * 36 + c16]      = acc0[r] + blo;
    obuf[(w * 16 + q * 4 + r) * 36 + 16 + c16] = acc1[r] + bhi;
  }
  __syncthreads();

  // ---- transposed store + per-wave stats partials (non-atomic) ----
  int t16 = threadIdx.x & 15, d8 = (threadIdx.x >> 4) & 15;
  float s[2] = {0.f, 0.f}, s2v[2] = {0.f, 0.f};
  #pragma unroll
  for (int tc = 0; tc < 4; tc++)
    #pragma unroll
    for (int hh = 0; hh < 2; hh++) {
      int d = d8 + hh * 16;
      float v = obuf[(tc * 16 + t16) * 36 + d];
      proj[((size_t)n * cC + d0 + d) * cHW + t0 + tc * 16 + t16] = v;
      s[hh] += v; s2v[hh] += v * v;
    }
  // within wave w, all lanes' d8 lie in one 4-wide band (w*4..w*4+3), so for
  // each hh the whole wave belongs to ONE GN2 group -> full-wave reduce.
  #pragma unroll
  for (int hh = 0; hh < 2; hh++) {
    float a = s[hh], b = s2v[hh];
    #pragma unroll
    for (int off = 32; off > 0; off >>= 1) {
      a += __shfl_down(a, off, 64);
      b += __shfl_down(b, off, 64);
    }
    if (L == 0) {
      int g = (d0 + w * 4 + hh * 16) >> 3;               // GN2 group 0..15
      size_t idx = (((size_t)(n * 16 + g) * 128) + blockIdx.x * 2 + (w & 1)) * 2;
      part2[idx]     = a;
      part2[idx + 1] = b;
    }
  }
}

// ---------------- GN2 apply + residual (recomputes xn from x) -------------
// part2 holds 128 non-atomic (sum,sumsq) partials per group
__global__ __launch_bounds__(256)
void gn2_apply(const float* __restrict__ x, const float* __restrict__ proj,
               const float* __restrict__ p1, const float* __restrict__ p2,
               const float* __restrict__ s1, const float* __restrict__ o1,
               const float* __restrict__ s2, const float* __restrict__ o2,
               float* __restrict__ out) {
  __shared__ float sb[2];
  int tid = blockIdx.x * 256 + threadIdx.x;
  int Cg = blockIdx.x;                   // == tid >> 8 (one (n,ch) per block)
  int n = Cg >> 7, ch = Cg & 127, g = ch >> 3, ng = n * 16 + g;
  // cooperative stats2 partial-sum (wave 0 sums 128 slots)
  if (threadIdx.x < 64) {
    int sl = threadIdx.x;
    float a = p2[((size_t)ng * 128 + sl) * 2]     + p2[((size_t)ng * 128 + 64 + sl) * 2];
    float b = p2[((size_t)ng * 128 + sl) * 2 + 1] + p2[((size_t)ng * 128 + 64 + sl) * 2 + 1];
    #pragma unroll
    for (int off = 32; off > 0; off >>= 1) {
      a += __shfl_down(a, off, 64);
      b += __shfl_down(b, off, 64);
    }
    if (threadIdx.x == 0) { sb[0] = a; sb[1] = b; }
  }
  float sa = 0.f, sbv = 0.f;
  #pragma unroll
  for (int p = 0; p < 8; p++) {
    sa += p1[(ng*8+p)*2]; sbv += p1[(ng*8+p)*2+1];
  }
  __syncthreads();
  float ta = sb[0], tb = sb[1];
  float mu1 = sa * (1.0f/32768.0f);
  float ri1 = rsqrtf(sbv * (1.0f/32768.0f) - mu1*mu1 + cEPS);
  float a1 = ri1 * s1[ch], b1 = o1[ch] - mu1 * a1;
  float mu2 = ta * (1.0f/32768.0f);
  float ri2 = rsqrtf(tb * (1.0f/32768.0f) - mu2*mu2 + cEPS);
  float a2 = ri2 * s2[ch], b2 = o2[ch] - mu2 * a2;
  const float4* x4 = (const float4*)x;
  const float4* pr4 = (const float4*)proj;
  float4* o4 = (float4*)out;
  #pragma unroll
  for (int i = 0; i < 4; i++) {
    size_t f = (size_t)tid * 4 + i;
    float4 xv = x4[f], pv = pr4[f];
    float4 r;
    r.x = xv.x * a1 + b1 + pv.x * a2 + b2;
    r.y = xv.y * a1 + b1 + pv.y * a2 + b2;
    r.z = xv.z * a1 + b1 + pv.z * a2 + b2;
    r.w = xv.w * a1 + b1 + pv.w * a2 + b2;
    o4[f] = r;
  }
}

// ---------------- launcher ------------------------------------------------
extern "C" void kernel_launch(void* const* d_in, const int* in_sizes, int n_in,
                              void* d_out, int out_size, void* d_ws, size_t ws_size,
                              hipStream_t stream) {
  const float* x     = (const float*)d_in[0];
  const float* w_qkv = (const float*)d_in[1];
  const float* b_qkv = (const float*)d_in[2];
  const float* w_out = (const float*)d_in[3];
  const float* b_out = (const float*)d_in[4];
  const float* g1s   = (const float*)d_in[5];
  const float* g1o   = (const float*)d_in[6];
  const float* g2s   = (const float*)d_in[7];
  const float* g2o   = (const float*)d_in[8];
  float* out = (float*)d_out;
  float* ws  = (float*)d_ws;

  const size_t MAP = (size_t)2 * cC * cHW;            // 1,048,576 elems
  float* proj    = ws;                                // 4 MB
  float* lpart   = proj + MAP;                        // SPLIT*32768 fl
  float* stats1  = lpart + (size_t)SPLIT * 32768;     // 512 fl
  float* part2   = stats1 + 512;                      // 8192 fl (GN2 partials)
  unsigned* opart = (unsigned*)(part2 + 8192);        // SPLIT*32768*16 u32 = 8 MB
  unsigned* qF   = opart + (size_t)SPLIT * 32768 * 16;  // 2 MB (fragment-major)
  unsigned* kF   = qF + MAP / 2;                      // 2 MB
  unsigned* vF   = kF + MAP / 2;                      // 2 MB
  unsigned short* xnB = (unsigned short*)(vF + MAP / 2);  // 2 MB
  unsigned short* wqT = xnB + MAP;                    // 96 KB
  unsigned short* woT = wqT + 49152;                  // 32 KB

  prep      <<<dim3(272),           256, 0, stream>>>(x, stats1, w_qkv, w_out, wqT, woT);
  gn1_pack  <<<dim3(16, 16, 2),     256, 0, stream>>>(x, stats1, g1s, g1o, xnB);
  qkv_mfma  <<<dim3(64, 12, 2),     256, 0, stream>>>(xnB, wqT, b_qkv, qF, kF, vF);
  flash_mfma<<<dim3(64, 8, SPLIT),  128, 0, stream>>>((const unsigned short*)qF,
                                                      (const unsigned short*)kF,
                                                      (const unsigned short*)vF,
                                                      opart, lpart);
  out_fused <<<dim3(64, 4, 2),      256, 0, stream>>>(opart, lpart, woT, b_out,
                                                      proj, part2);
  gn2_apply <<<dim3(256),           256, 0, stream>>>(x, proj, stats1, part2,
                                                      g1s, g1o, g2s, g2o, out);
}

// Round 12
// 124.844 us; speedup vs baseline: 1.0123x; 1.0123x over previous
//
#include <hip/hip_runtime.h>
#include <hip/hip_bf16.h>
#include <math.h>

// Problem constants
constexpr int cHW   = 4096;   // H*W
constexpr int cC    = 128;
constexpr int cNH   = 4;
constexpr int cDH   = 32;
constexpr float cEPS = 1e-5f;
// dh^-0.5 * log2(e): scores in log2 domain, softmax via exp2, fixed max=0
constexpr float cQS = 0.2550347805f;
// SPLIT=4 (R5/R6: SPLIT=8 costs opart traffic; flash concurrency parked).
// R10 structure (124.9us best): fused out_fused (in-register combine,
// non-atomic stats partials). R11 prefetch was neutral -> reverted.
// R12: GN1 fused into qkv_mfma (LDS preamble computes per-channel a,b from
// stats1; loads x fp32 directly) - removes gn1_pack launch + xnB round-trip.
constexpr int SPLIT = 4;

typedef short bh8  __attribute__((ext_vector_type(8)));   // 8 bf16 (4 VGPRs)
typedef float f4   __attribute__((ext_vector_type(4)));   // MFMA C/D 16x16
typedef float f16a __attribute__((ext_vector_type(16)));  // MFMA C/D 32x32

static __device__ __forceinline__ unsigned short f2bf(float f) {
  union { __hip_bfloat16 h; unsigned short u; } cv;
  cv.h = __float2bfloat16(f);
  return cv.u;
}
static __device__ __forceinline__ unsigned pack2bf(float a, float b) {
  return (unsigned)f2bf(a) | ((unsigned)f2bf(b) << 16);
}
// truncating pack: 2 VALU. Error cancels in softmax since l is computed from
// the same truncated P via MFMA-with-ones.
static __device__ __forceinline__ unsigned pack_trunc(float a, float b) {
  unsigned ua = __builtin_bit_cast(unsigned, a);
  unsigned ub = __builtin_bit_cast(unsigned, b);
  return (ua >> 16) | (ub & 0xffff0000u);
}
static __device__ __forceinline__ float bflo(unsigned pk) {
  return __builtin_bit_cast(float, pk << 16);
}
static __device__ __forceinline__ float bfhi(unsigned pk) {
  return __builtin_bit_cast(float, pk & 0xffff0000u);
}
// v_permlane32_swap_b32: dst lanes 32-63 <-> src lanes 0-31
static __device__ __forceinline__ void plswap(unsigned& a, unsigned& b) {
#if __has_builtin(__builtin_amdgcn_permlane32_swap)
  typedef int v2i __attribute__((ext_vector_type(2)));
  v2i r = __builtin_amdgcn_permlane32_swap((int)a, (int)b, false, false);
  a = (unsigned)r[0]; b = (unsigned)r[1];
#else
  asm("v_permlane32_swap_b32 %0, %1" : "+v"(a), "+v"(b));
#endif
}
static __device__ __forceinline__ bh8 mk8(unsigned a, unsigned b, unsigned c, unsigned d) {
  union { unsigned u[4]; bh8 v; } t;
  t.u[0] = a; t.u[1] = b; t.u[2] = c; t.u[3] = d;
  return t.v;
}

// ---------------- block reduce (sum of two values over 256 threads) -------
__device__ __forceinline__ void block_reduce2(float& a, float& b, float* sbuf) {
  #pragma unroll
  for (int off = 32; off > 0; off >>= 1) {
    a += __shfl_down(a, off, 64);
    b += __shfl_down(b, off, 64);
  }
  int wave = threadIdx.x >> 6;
  int lane = threadIdx.x & 63;
  if (lane == 0) { sbuf[wave] = a; sbuf[4 + wave] = b; }
  __syncthreads();
  if (threadIdx.x == 0) {
    sbuf[8] = sbuf[0] + sbuf[1] + sbuf[2] + sbuf[3];
    sbuf[9] = sbuf[4] + sbuf[5] + sbuf[6] + sbuf[7];
  }
  __syncthreads();
  a = sbuf[8];
  b = sbuf[9];
}

// ---------------- prep: GN1 stats partials + weight transpose/pack --------
__global__ __launch_bounds__(256)
void prep(const float* __restrict__ x, float* __restrict__ part,
          const float* __restrict__ wq, const float* __restrict__ wo,
          unsigned short* __restrict__ wqT, unsigned short* __restrict__ woT) {
  __shared__ float lds[32 * 133];
  int L = threadIdx.x;
  if (blockIdx.x < 256) {
    int ng = blockIdx.x >> 3, sl = blockIdx.x & 7;
    const float4* s4 = (const float4*)x;
    float s = 0.f, s2 = 0.f;
    #pragma unroll
    for (int i = 0; i < 4; i++) {
      int idx = i * 256 + L;
      int c = idx >> 7, tt = idx & 127;
      float4 v = s4[(size_t)(ng * 8 + c) * 1024 + sl * 128 + tt];
      s  += v.x + v.y + v.z + v.w;
      s2 += v.x*v.x + v.y*v.y + v.z*v.z + v.w*v.w;
    }
    block_reduce2(s, s2, lds);
    if (L == 0) { part[blockIdx.x * 2] = s; part[blockIdx.x * 2 + 1] = s2; }
  } else {
    int bx = blockIdx.x - 256;
    const float* src; unsigned short* dst; int W, d0;
    if (bx < 12) { src = wq; dst = wqT; W = 384; d0 = bx * 32; }
    else         { src = wo; dst = woT; W = 128; d0 = (bx - 12) * 32; }
    #pragma unroll
    for (int i = 0; i < 16; i++) {
      int c = i * 8 + (L >> 5), d = L & 31;
      lds[d * 133 + c] = src[(size_t)c * W + d0 + d];
    }
    __syncthreads();
    int d = L >> 3, ch = L & 7, c0 = ch * 16;
    unsigned pk[8];
    #pragma unroll
    for (int j = 0; j < 8; j++)
      pk[j] = pack2bf(lds[d * 133 + c0 + 2 * j], lds[d * 133 + c0 + 2 * j + 1]);
    uint4* d4 = (uint4*)(dst + (size_t)(d0 + d) * 128 + c0);
    d4[0] = make_uint4(pk[0], pk[1], pk[2], pk[3]);
    d4[1] = make_uint4(pk[4], pk[5], pk[6], pk[7]);
  }
}

// ---------------- QKV projection (MFMA) with FUSED GN1 --------------------
// grid (64 tt, 12 dg, 2 n), block 256 (4 waves x 16 t-rows).
// R12: reads x (fp32) directly; LDS preamble builds per-channel GN1 (a,b)
// from stats1 partials (group == 8-channel chunk cc). Same pack2bf rounding
// as the old xnB path -> bit-identical A-fragments, one less kernel + no
// xnB round-trip. x is 4MB (L2/L3-hot for the 12x dg re-reads).
// Output layouts (unchanged) are exactly the order flash_mfma consumes:
//   qF/kF: [nh][tile=key/32][frag=dh/16][L=hi*32+col] bh8
//   vF   : [nh][tile]       [frag=kk/16][L=hi*32+col] bh8
__global__ __launch_bounds__(256)
void qkv_mfma(const float* __restrict__ x, const float* __restrict__ part,
              const float* __restrict__ sc, const float* __restrict__ of,
              const unsigned short* __restrict__ wqT,
              const float* __restrict__ bq, unsigned* __restrict__ qF,
              unsigned* __restrict__ kF, unsigned* __restrict__ vF) {
  __shared__ float vbuf[64 * 36];
  __shared__ float a1s[128], b1s[128];
  const int L = threadIdx.x & 63, w = threadIdx.x >> 6;
  const int c16 = L & 15, q = L >> 4;
  const int t0 = blockIdx.x * 64, dg = blockIdx.y, n = blockIdx.z;
  const int nh = n * 4 + (dg & 3), d0 = dg * 32;
  const f4 zf = {0.f, 0.f, 0.f, 0.f};
  f4 acc0 = zf, acc1 = zf;
  const int trow = t0 + w * 16 + c16;

  // ---- GN1 coefficient preamble (one group == channels ch>>3) ----
  if (threadIdx.x < 128) {
    const int ch = threadIdx.x, ng = n * 16 + (ch >> 3);
    float s = 0.f, s2 = 0.f;
    #pragma unroll
    for (int p = 0; p < 8; p++) { s += part[(ng*8+p)*2]; s2 += part[(ng*8+p)*2+1]; }
    float mu = s * (1.0f / 32768.0f);
    float rinv = rsqrtf(s2 * (1.0f / 32768.0f) - mu * mu + cEPS);
    float a = rinv * sc[ch];
    a1s[ch] = a;
    b1s[ch] = of[ch] - mu * a;
  }
  __syncthreads();

  #pragma unroll
  for (int ks = 0; ks < 4; ks++) {
    const int c0 = (ks * 4 + q) * 8;
    const float* xp = x + ((size_t)n * cC + c0) * cHW + trow;
    float vv[8];
    #pragma unroll
    for (int j = 0; j < 8; j++)
      vv[j] = xp[(size_t)j * cHW] * a1s[c0 + j] + b1s[c0 + j];
    bh8 a = mk8(pack2bf(vv[0], vv[1]), pack2bf(vv[2], vv[3]),
                pack2bf(vv[4], vv[5]), pack2bf(vv[6], vv[7]));
    bh8 b0 = *(const bh8*)(wqT + (size_t)(d0 + c16) * 128 + ks * 32 + q * 8);
    bh8 b1 = *(const bh8*)(wqT + (size_t)(d0 + 16 + c16) * 128 + ks * 32 + q * 8);
    acc0 = __builtin_amdgcn_mfma_f32_16x16x32_bf16(a, b0, acc0, 0, 0, 0);
    acc1 = __builtin_amdgcn_mfma_f32_16x16x32_bf16(a, b1, acc1, 0, 0, 0);
  }
  const float blo = bq[d0 + c16], bhi = bq[d0 + 16 + c16];
  const float scl = (dg < 4) ? cQS : 1.0f;
  // stage [row=t-t0][dh 0..31] (pad 36)
  #pragma unroll
  for (int r = 0; r < 4; r++) {
    vbuf[(w * 16 + q * 4 + r) * 36 + c16]      = (acc0[r] + blo) * scl;
    vbuf[(w * 16 + q * 4 + r) * 36 + 16 + c16] = (acc1[r] + bhi) * scl;
  }
  __syncthreads();
  // fragment-major pack: 256 threads = 2 tiles x 2 frags x 64 lanes
  const int tl = threadIdx.x >> 7, fr = (threadIdx.x >> 6) & 1, LL = threadIdx.x & 63;
  const int col = LL & 31, h2 = LL >> 5;
  unsigned pk[4];
  if (dg < 8) {
    const float* src = &vbuf[(tl * 32 + col) * 36 + fr * 16 + h2 * 8];
    #pragma unroll
    for (int jj = 0; jj < 4; jj++) pk[jj] = pack2bf(src[2 * jj], src[2 * jj + 1]);
  } else {
    const float* src = &vbuf[(tl * 32 + fr * 16 + h2 * 8) * 36 + col];
    #pragma unroll
    for (int jj = 0; jj < 4; jj++) pk[jj] = pack2bf(src[2 * jj * 36], src[(2 * jj + 1) * 36]);
  }
  unsigned* dst = (dg < 4) ? qF : ((dg < 8) ? kF : vF);
  size_t frag = ((size_t)(nh * 128 + (t0 >> 5) + tl) * 2 + fr) * 64 + LL;
  ((uint4*)dst)[frag] = make_uint4(pk[0], pk[1], pk[2], pk[3]);
}

// ---------------- MFMA flash attention, swapped-QK 32x32, zero LDS --------
// R10-proven config (124.9us): block 128 (2 waves, 1 q-tile each),
// grid (64 qb, 8 nh, SPLIT). Latency-bound at 4 chains/SIMD (invariant under
// wave repackaging R7/R9; load prefetch neutral R11 -> plain loop).
__global__ __launch_bounds__(128, 4)
void flash_mfma(const unsigned short* __restrict__ qF,
                const unsigned short* __restrict__ kF,
                const unsigned short* __restrict__ vF,
                unsigned* __restrict__ opart, float* __restrict__ lpart) {
  const int w = threadIdx.x >> 6, L = threadIdx.x & 63;
  const int col = L & 31, hi = L >> 5;
  const int qt = blockIdx.x * 2 + w, nh = blockIdx.y, ph = blockIdx.z;
  const short oneb = 0x3F80;        // bf16 1.0
  const bh8 ones = {oneb, oneb, oneb, oneb, oneb, oneb, oneb, oneb};
  const f16a zf16 = {0.f,0.f,0.f,0.f, 0.f,0.f,0.f,0.f, 0.f,0.f,0.f,0.f, 0.f,0.f,0.f,0.f};

  // Q fragments (coalesced: lane L reads 16B at L*16)
  const unsigned short* qb = qF + ((size_t)(nh * 128 + qt) * 2) * 512;
  bh8 qf0 = *(const bh8*)(qb + L * 8);
  bh8 qf1 = *(const bh8*)(qb + 512 + L * 8);

  const unsigned short* kb = kF + (size_t)nh * 128 * 1024;
  const unsigned short* vb = vF + (size_t)nh * 128 * 1024;

  f16a o = zf16, lacc = zf16;

  const int tb0 = ph * (cHW / SPLIT / 32);   // 32 key-tiles per split
  #pragma unroll 2
  for (int tl = tb0; tl < tb0 + (cHW / SPLIT / 32); ++tl) {
    const unsigned short* kp = kb + (size_t)tl * 1024;
    const unsigned short* vp = vb + (size_t)tl * 1024;
    bh8 ka0 = *(const bh8*)(kp + L * 8);
    bh8 ka1 = *(const bh8*)(kp + 512 + L * 8);
    bh8 vfa = *(const bh8*)(vp + L * 8);
    bh8 vfb = *(const bh8*)(vp + 512 + L * 8);
    f16a s = __builtin_amdgcn_mfma_f32_32x32x16_bf16(ka0, qf0, zf16, 0, 0, 0);
    s = __builtin_amdgcn_mfma_f32_32x32x16_bf16(ka1, qf1, s, 0, 0, 0);
    // softmax numerator (fixed max 0), truncating bf16 pack
    #pragma unroll
    for (int r = 0; r < 16; r++) s[r] = __builtin_amdgcn_exp2f(s[r]);
    // pk holds key pairs; lane(hi) owns keys (reg&3)+8*(reg>>2)+4*hi
    unsigned pk0 = pack_trunc(s[0],  s[1]);
    unsigned pk1 = pack_trunc(s[2],  s[3]);
    unsigned pk2 = pack_trunc(s[4],  s[5]);
    unsigned pk3 = pack_trunc(s[6],  s[7]);
    unsigned pk4 = pack_trunc(s[8],  s[9]);
    unsigned pk5 = pack_trunc(s[10], s[11]);
    unsigned pk6 = pack_trunc(s[12], s[13]);
    unsigned pk7 = pack_trunc(s[14], s[15]);
    // redistribute into A-frag word order: one swap yields words 0 and 2
    plswap(pk0, pk2); plswap(pk1, pk3);   // keys tile+0..15
    plswap(pk4, pk6); plswap(pk5, pk7);   // keys tile+16..31
    bh8 pf0 = mk8(pk0, pk1, pk2, pk3);
    bh8 pf1 = mk8(pk4, pk5, pk6, pk7);
    o    = __builtin_amdgcn_mfma_f32_32x32x16_bf16(pf0, vfa,  o,    0, 0, 0);
    lacc = __builtin_amdgcn_mfma_f32_32x32x16_bf16(pf0, ones, lacc, 0, 0, 0);
    o    = __builtin_amdgcn_mfma_f32_32x32x16_bf16(pf1, vfb,  o,    0, 0, 0);
    lacc = __builtin_amdgcn_mfma_f32_32x32x16_bf16(pf1, ones, lacc, 0, 0, 0);
  }

  // epilogue: lane(hi,col) holds O[row][d=col] for rows (reg&3)+8*(reg>>2)+4*hi.
  // opart: u32 packs ROW pairs (even,odd) at [(globalrow/2)*32 + d].
  const size_t base = (size_t)ph * 32768 + (size_t)nh * cHW + (size_t)qt * 32;
  #pragma unroll
  for (int k = 0; k < 8; k++) {
    const int rowlo = ((2 * k) & 3) + 8 * (k >> 1) + 4 * hi;
    opart[((base + rowlo) >> 1) * 32 + col] = pack_trunc(o[2 * k], o[2 * k + 1]);
  }
  if (col == 0) {
    #pragma unroll
    for (int r = 0; r < 16; r++)
      lpart[base + (r & 3) + 8 * (r >> 2) + 4 * hi] = lacc[r];
  }
}

// ---------------- fused: in-register combine + out projection + stats -----
// grid (64 tt, 4 dg, 2 n), block 256 (4 waves) — R10-proven form.
// In-register split-K combine feeds the out-projection A-fragments directly;
// GN2 stats as per-(block,wave,hh) NON-atomic partials (R8 lesson).
// part2 layout: [n][g 16][slot 128 = tt*2+(w&1)][2: sum,sumsq]
__global__ __launch_bounds__(256)
void out_fused(const unsigned* __restrict__ opart, const float* __restrict__ lpart,
               const unsigned short* __restrict__ woT, const float* __restrict__ bo,
               float* __restrict__ proj, float* __restrict__ part2) {
  __shared__ float obuf[64 * 36];
  const int L = threadIdx.x & 63, w = threadIdx.x >> 6;
  const int c16 = L & 15, q = L >> 4;
  const int t0 = blockIdx.x * 64, d0 = blockIdx.y * 32, n = blockIdx.z;
  const f4 zf = {0.f, 0.f, 0.f, 0.f};
  const int trow = t0 + w * 16 + c16;

  // ---- in-register split-K combine: A-fragment per head ----
  bh8 afrag[4];
  #pragma unroll
  for (int h = 0; h < 4; h++) {
    const size_t grow = (size_t)(n * 4 + h) * cHW + trow;
    float l = 0.f;
    #pragma unroll
    for (int p = 0; p < SPLIT; p++) l += lpart[(size_t)p * 32768 + grow];
    const size_t rp = grow >> 1;
    const int par = c16 & 1;            // row parity: lo=even row, hi=odd
    float e[8];
    #pragma unroll
    for (int j = 0; j < 8; j++) e[j] = 0.f;
    #pragma unroll
    for (int p = 0; p < SPLIT; p++) {
      const uint4* op = (const uint4*)(opart + ((size_t)p * 16384 + rp) * 32 + q * 8);
      uint4 v0 = op[0], v1 = op[1];
      unsigned uu[8] = {v0.x, v0.y, v0.z, v0.w, v1.x, v1.y, v1.z, v1.w};
      #pragma unroll
      for (int j = 0; j < 8; j++)
        e[j] += par ? bfhi(uu[j]) : bflo(uu[j]);
    }
    const float inv = 1.0f / l;
    unsigned pk[4];
    #pragma unroll
    for (int jj = 0; jj < 4; jj++)
      pk[jj] = pack2bf(e[2 * jj] * inv, e[2 * jj + 1] * inv);
    afrag[h] = mk8(pk[0], pk[1], pk[2], pk[3]);
  }

  // ---- out-projection MFMA (A straight from registers) ----
  f4 acc0 = zf, acc1 = zf;
  #pragma unroll
  for (int h = 0; h < 4; h++) {
    bh8 b0 = *(const bh8*)(woT + (size_t)(d0 + c16) * 128 + h * 32 + q * 8);
    bh8 b1 = *(const bh8*)(woT + (size_t)(d0 + 16 + c16) * 128 + h * 32 + q * 8);
    acc0 = __builtin_amdgcn_mfma_f32_16x16x32_bf16(afrag[h], b0, acc0, 0, 0, 0);
    acc1 = __builtin_amdgcn_mfma_f32_16x16x32_bf16(afrag[h], b1, acc1, 0, 0, 0);
  }
  float blo = bo[d0 + c16], bhi = bo[d0 + 16 + c16];
  #pragma unroll
  for (int r = 0; r < 4; r++) {
    obuf[(w * 16 + q * 4 + r) * 36 + c16]      = acc0[r] + blo;
    obuf[(w * 16 + q * 4 + r) * 36 + 16 + c16] = acc1[r] + bhi;
  }
  __syncthreads();

  // ---- transposed store + per-wave stats partials (non-atomic) ----
  int t16 = threadIdx.x & 15, d8 = (threadIdx.x >> 4) & 15;
  float s[2] = {0.f, 0.f}, s2v[2] = {0.f, 0.f};
  #pragma unroll
  for (int tc = 0; tc < 4; tc++)
    #pragma unroll
    for (int hh = 0; hh < 2; hh++) {
      int d = d8 + hh * 16;
      float v = obuf[(tc * 16 + t16) * 36 + d];
      proj[((size_t)n * cC + d0 + d) * cHW + t0 + tc * 16 + t16] = v;
      s[hh] += v; s2v[hh] += v * v;
    }
  // within wave w, all lanes' d8 lie in one 4-wide band (w*4..w*4+3), so for
  // each hh the whole wave belongs to ONE GN2 group -> full-wave reduce.
  #pragma unroll
  for (int hh = 0; hh < 2; hh++) {
    float a = s[hh], b = s2v[hh];
    #pragma unroll
    for (int off = 32; off > 0; off >>= 1) {
      a += __shfl_down(a, off, 64);
      b += __shfl_down(b, off, 64);
    }
    if (L == 0) {
      int g = (d0 + w * 4 + hh * 16) >> 3;               // GN2 group 0..15
      size_t idx = (((size_t)(n * 16 + g) * 128) + blockIdx.x * 2 + (w & 1)) * 2;
      part2[idx]     = a;
      part2[idx + 1] = b;
    }
  }
}

// ---------------- GN2 apply + residual (recomputes xn from x) -------------
// part2 holds 128 non-atomic (sum,sumsq) partials per group
__global__ __launch_bounds__(256)
void gn2_apply(const float* __restrict__ x, const float* __restrict__ proj,
               const float* __restrict__ p1, const float* __restrict__ p2,
               const float* __restrict__ s1, const float* __restrict__ o1,
               const float* __restrict__ s2, const float* __restrict__ o2,
               float* __restrict__ out) {
  __shared__ float sb[2];
  int tid = blockIdx.x * 256 + threadIdx.x;
  int Cg = blockIdx.x;                   // == tid >> 8 (one (n,ch) per block)
  int n = Cg >> 7, ch = Cg & 127, g = ch >> 3, ng = n * 16 + g;
  // cooperative stats2 partial-sum (wave 0 sums 128 slots)
  if (threadIdx.x < 64) {
    int sl = threadIdx.x;
    float a = p2[((size_t)ng * 128 + sl) * 2]     + p2[((size_t)ng * 128 + 64 + sl) * 2];
    float b = p2[((size_t)ng * 128 + sl) * 2 + 1] + p2[((size_t)ng * 128 + 64 + sl) * 2 + 1];
    #pragma unroll
    for (int off = 32; off > 0; off >>= 1) {
      a += __shfl_down(a, off, 64);
      b += __shfl_down(b, off, 64);
    }
    if (threadIdx.x == 0) { sb[0] = a; sb[1] = b; }
  }
  float sa = 0.f, sbv = 0.f;
  #pragma unroll
  for (int p = 0; p < 8; p++) {
    sa += p1[(ng*8+p)*2]; sbv += p1[(ng*8+p)*2+1];
  }
  __syncthreads();
  float ta = sb[0], tb = sb[1];
  float mu1 = sa * (1.0f/32768.0f);
  float ri1 = rsqrtf(sbv * (1.0f/32768.0f) - mu1*mu1 + cEPS);
  float a1 = ri1 * s1[ch], b1 = o1[ch] - mu1 * a1;
  float mu2 = ta * (1.0f/32768.0f);
  float ri2 = rsqrtf(tb * (1.0f/32768.0f) - mu2*mu2 + cEPS);
  float a2 = ri2 * s2[ch], b2 = o2[ch] - mu2 * a2;
  const float4* x4 = (const float4*)x;
  const float4* pr4 = (const float4*)proj;
  float4* o4 = (float4*)out;
  #pragma unroll
  for (int i = 0; i < 4; i++) {
    size_t f = (size_t)tid * 4 + i;
    float4 xv = x4[f], pv = pr4[f];
    float4 r;
    r.x = xv.x * a1 + b1 + pv.x * a2 + b2;
    r.y = xv.y * a1 + b1 + pv.y * a2 + b2;
    r.z = xv.z * a1 + b1 + pv.z * a2 + b2;
    r.w = xv.w * a1 + b1 + pv.w * a2 + b2;
    o4[f] = r;
  }
}

// ---------------- launcher ------------------------------------------------
extern "C" void kernel_launch(void* const* d_in, const int* in_sizes, int n_in,
                              void* d_out, int out_size, void* d_ws, size_t ws_size,
                              hipStream_t stream) {
  const float* x     = (const float*)d_in[0];
  const float* w_qkv = (const float*)d_in[1];
  const float* b_qkv = (const float*)d_in[2];
  const float* w_out = (const float*)d_in[3];
  const float* b_out = (const float*)d_in[4];
  const float* g1s   = (const float*)d_in[5];
  const float* g1o   = (const float*)d_in[6];
  const float* g2s   = (const float*)d_in[7];
  const float* g2o   = (const float*)d_in[8];
  float* out = (float*)d_out;
  float* ws  = (float*)d_ws;

  const size_t MAP = (size_t)2 * cC * cHW;            // 1,048,576 elems
  float* proj    = ws;                                // 4 MB
  float* lpart   = proj + MAP;                        // SPLIT*32768 fl
  float* stats1  = lpart + (size_t)SPLIT * 32768;     // 512 fl
  float* part2   = stats1 + 512;                      // 8192 fl (GN2 partials)
  unsigned* opart = (unsigned*)(part2 + 8192);        // SPLIT*32768*16 u32 = 8 MB
  unsigned* qF   = opart + (size_t)SPLIT * 32768 * 16;  // 2 MB (fragment-major)
  unsigned* kF   = qF + MAP / 2;                      // 2 MB
  unsigned* vF   = kF + MAP / 2;                      // 2 MB
  unsigned short* wqT = (unsigned short*)(vF + MAP / 2);  // 96 KB
  unsigned short* woT = wqT + 49152;                  // 32 KB

  prep      <<<dim3(272),           256, 0, stream>>>(x, stats1, w_qkv, w_out, wqT, woT);
  qkv_mfma  <<<dim3(64, 12, 2),     256, 0, stream>>>(x, stats1, g1s, g1o, wqT,
                                                      b_qkv, qF, kF, vF);
  flash_mfma<<<dim3(64, 8, SPLIT),  128, 0, stream>>>((const unsigned short*)qF,
                                                      (const unsigned short*)kF,
                                                      (const unsigned short*)vF,
                                                      opart, lpart);
  out_fused <<<dim3(64, 4, 2),      256, 0, stream>>>(opart, lpart, woT, b_out,
                                                      proj, part2);
  gn2_apply <<<dim3(256),           256, 0, stream>>>(x, proj, stats1, part2,
                                                      g1s, g1o, g2s, g2o, out);
}